// Round 1
// baseline (522.277 us; speedup 1.0000x reference)
//
#include <hip/hip_runtime.h>

#define NBINS 15
#define TPB   256
#define GRID  1536                 // 256 CU x 6 blocks/CU (LDS-bound) = one generation
#define NROWS (3 * NBINS)          // rows: [0,15)=count, [15,30)=conf, [30,45)=acc
#define HCOLS 128                  // histogram columns; shared by tid and tid+128
#define HSIZE (NROWS * HCOLS)      // 5760 floats = 23040 B LDS -> 6 blocks/CU

// ---------------------------------------------------------------------------
// O(1) binning. Membership predicate is IDENTICAL to the verified suffix
// kernel: bin b = { c : c > b*(1/15.0f)  &&  !(c > (b+1)*(1/15.0f)) }.
// b0 = trunc(c*15) is within +-1 of the true bin (|fl(15c) - 15*bound_j| <
// 1e-5 << bin width), so one exact up-check and one exact down-check against
// the same boundary formula recover the exact bin. Invalid c (<=0 or >1)
// gets w=0 and contributes ds_add of 0.0 (harmless).
// Cost: ~18 VALU + 3 ds_add_f32 per element (vs ~77 VALU in the suffix ladder).
__device__ __forceinline__ void ece_elem(float c, float a, float* __restrict__ col) {
    const float INV15 = 1.0f / 15.0f;
    float t  = c * 15.0f;
    float f0 = truncf(t);                         // integer-valued, exact for small ints
    int   b  = (int)f0;
    b += (c > (f0 + 1.0f) * INV15) ? 1 : 0;       // exact predicate: c > bound(b0+1)
    b -= (c <= f0 * INV15)         ? 1 : 0;       // exact predicate: c <= bound(b0)
    b = min(max(b, 0), NBINS - 1);
    float w = (c > 0.0f && c <= 1.0f) ? 1.0f : 0.0f;
    float* p = col + (b << 7);                    // b * HCOLS; bank = tid%32, conflict-free
    atomicAdd(p,                     w);          // ds_add_f32 offset:0
    atomicAdd(p + NBINS * HCOLS,     w * c);      // ds_add_f32 offset:7680
    atomicAdd(p + 2 * NBINS * HCOLS, w * a);      // ds_add_f32 offset:15360
}

__global__ __launch_bounds__(TPB, 4) void ece_partial(const float* __restrict__ conf,
                                                      const float* __restrict__ acc,
                                                      float* __restrict__ ws,
                                                      int N, int slotMode) {
    __shared__ float hist[HSIZE];
    const int tid  = threadIdx.x;
    const int lane = tid & 63;
    const int wid  = tid >> 6;

    for (int i = tid; i < HSIZE; i += TPB) hist[i] = 0.0f;
    __syncthreads();

    float* col = &hist[tid & (HCOLS - 1)];

    const int gid    = blockIdx.x * TPB + tid;
    const int stride = GRID * TPB;
    const float4* c4 = (const float4*)conf;
    const float4* a4 = (const float4*)acc;
    const int N8 = N >> 3;

    // register double-buffered main loop: issue next iteration's 4x dwordx4
    // before processing the current 8 elements, so HBM latency hides under
    // the ~140 VALU ops of the current batch.
    int  p    = gid;
    bool have = p < N8;
    float4 c0, c1, a0, a1;
    if (have) {
        c0 = c4[2 * p]; c1 = c4[2 * p + 1];
        a0 = a4[2 * p]; a1 = a4[2 * p + 1];
    }
    while (have) {
        const int  pn = p + stride;
        const bool hn = pn < N8;
        const int  pl = hn ? pn : p;              // clamp: always-valid prefetch addr
        float4 d0 = c4[2 * pl], d1 = c4[2 * pl + 1];
        float4 e0 = a4[2 * pl], e1 = a4[2 * pl + 1];

        ece_elem(c0.x, a0.x, col);
        ece_elem(c0.y, a0.y, col);
        ece_elem(c0.z, a0.z, col);
        ece_elem(c0.w, a0.w, col);
        ece_elem(c1.x, a1.x, col);
        ece_elem(c1.y, a1.y, col);
        ece_elem(c1.z, a1.z, col);
        ece_elem(c1.w, a1.w, col);

        c0 = d0; c1 = d1; a0 = e0; a1 = e1;
        p = pn; have = hn;
    }

    // tail (no-op for N = 2^25); no wave-uniformity requirement anymore
    for (int i = (N8 << 3) + gid; i < N; i += stride)
        ece_elem(conf[i], acc[i], col);

    __syncthreads();

    // block reduce: wave w handles rows w, w+4, ...; lane reads 2 columns
    // (HCOLS=128), butterfly over 64 lanes, lane 0 publishes.
    for (int r = wid; r < NROWS; r += 4) {
        float s = hist[r * HCOLS + lane] + hist[r * HCOLS + 64 + lane];
        #pragma unroll
        for (int sft = 32; sft >= 1; sft >>= 1) s += __shfl_xor(s, sft);
        if (lane == 0) {
            if (slotMode) ws[r * GRID + blockIdx.x] = s;   // block partial, exact-ish f32
            else          atomicAdd(&ws[r], s);
        }
    }
}

// ---------------------------------------------------------------------------
// Slot-mode final: reduce 45 rows x GRID columns in f64, then ECE.
__global__ __launch_bounds__(1024) void ece_final_slots(const float* __restrict__ ws,
                                                        float* __restrict__ out, int N) {
    __shared__ double red[NROWS];
    const int tid = threadIdx.x, lane = tid & 63, w = tid >> 6;
    for (int r = w; r < NROWS; r += 16) {
        double s = 0.0;
        #pragma unroll 4
        for (int it = 0; it < GRID / 64; ++it)
            s += (double)ws[r * GRID + it * 64 + lane];
        #pragma unroll
        for (int sft = 32; sft >= 1; sft >>= 1) s += __shfl_xor(s, sft);
        if (lane == 0) red[r] = s;
    }
    __syncthreads();
    if (w == 0) {
        double per = 0.0;
        if (lane < NBINS) {
            double cnt = red[lane];
            double cs  = red[NBINS + lane];
            double as  = red[2 * NBINS + lane];
            double safe = cnt > 1.0 ? cnt : 1.0;
            double d = cs / safe - as / safe;
            per = (cnt > 0.0) ? d * d * (cnt / (double)N) : 0.0;
        }
        per += __shfl_down(per, 8);
        per += __shfl_down(per, 4);
        per += __shfl_down(per, 2);
        per += __shfl_down(per, 1);
        if (lane == 0) out[0] = (float)per;
    }
}

// ---------------------------------------------------------------------------
// Atomic-mode fallback (tiny ws): zero + atomic partials + tiny final.
__global__ void ece_zero_ws(float* __restrict__ ws) {
    int t = threadIdx.x;
    if (t < NROWS) ws[t] = 0.0f;
}

__global__ void ece_final_atomic(const float* __restrict__ ws,
                                 float* __restrict__ out, int N) {
    int lane = threadIdx.x;
    double per = 0.0;
    if (lane < NBINS) {
        double cnt = (double)ws[lane];
        double cs  = (double)ws[NBINS + lane];
        double as  = (double)ws[2 * NBINS + lane];
        double safe = cnt > 1.0 ? cnt : 1.0;
        double d = cs / safe - as / safe;
        per = (cnt > 0.0) ? d * d * (cnt / (double)N) : 0.0;
    }
    per += __shfl_down(per, 8);
    per += __shfl_down(per, 4);
    per += __shfl_down(per, 2);
    per += __shfl_down(per, 1);
    if (lane == 0) out[0] = (float)per;
}

// ---------------------------------------------------------------------------
extern "C" void kernel_launch(void* const* d_in, const int* in_sizes, int n_in,
                              void* d_out, int out_size, void* d_ws, size_t ws_size,
                              hipStream_t stream) {
    const float* conf = (const float*)d_in[0];
    const float* acc  = (const float*)d_in[1];
    float* out = (float*)d_out;
    float* ws  = (float*)d_ws;
    const int N = in_sizes[0];

    const size_t need = (size_t)NROWS * GRID * sizeof(float);
    const int slotMode = (ws_size >= need) ? 1 : 0;

    if (!slotMode) ece_zero_ws<<<1, 64, 0, stream>>>(ws);
    ece_partial<<<GRID, TPB, 0, stream>>>(conf, acc, ws, N, slotMode);
    if (slotMode) ece_final_slots<<<1, 1024, 0, stream>>>(ws, out, N);
    else          ece_final_atomic<<<1, 64, 0, stream>>>(ws, out, N);
}